// Round 7
// baseline (172.959 us; speedup 1.0000x reference)
//
#include <hip/hip_runtime.h>
#include <hip/hip_bf16.h>

#define EMBED 1024
#define WINDOW 512
#define NROWS 16384  // 4 * 4096

typedef __attribute__((ext_vector_type(4))) float f32x4;
typedef __bf16 bf16x8 __attribute__((ext_vector_type(8)));

#define GLDS(g, l)                                                        \
  __builtin_amdgcn_global_load_lds(                                       \
      (const __attribute__((address_space(1))) void*)(const void*)(g),    \
      (__attribute__((address_space(3))) void*)(void*)(l), 16, 0, 0)

// ---------------- prep: fp32 -> bf16 cast, 8 elems/thread ----------------
__global__ __launch_bounds__(256) void cast_bf16_kernel(
    const float* __restrict__ in, __bf16* __restrict__ out, int n8) {
  int i = blockIdx.x * blockDim.x + threadIdx.x;
  if (i >= n8) return;
  const f32x4* p = (const f32x4*)(in + (size_t)i * 8);
  f32x4 a = p[0], b = p[1];
  bf16x8 o = {(__bf16)a[0], (__bf16)a[1], (__bf16)a[2], (__bf16)a[3],
              (__bf16)b[0], (__bf16)b[1], (__bf16)b[2], (__bf16)b[3]};
  *(bf16x8*)(out + (size_t)i * 8) = o;
}

// ---------------- prep: MB [512][1024] fp32 -> MB^T [1024][512] bf16 ------
__global__ __launch_bounds__(256) void transpose_mb_kernel(
    const float* __restrict__ mb, __bf16* __restrict__ mbt) {
  int idx = blockIdx.x * blockDim.x + threadIdx.x;  // over 512*1024
  int w = idx >> 10, d = idx & 1023;
  mbt[(size_t)d * WINDOW + w] = (__bf16)mb[idx];
}

// ---------------- softmax in-place on S1 rows (512 wide) -----------------
__global__ __launch_bounds__(256) void softmax_kernel(__bf16* __restrict__ s1) {
  const int row = blockIdx.x * 4 + (threadIdx.x >> 6);
  const int lane = threadIdx.x & 63;
  __bf16* p = s1 + (size_t)row * WINDOW + lane * 8;
  bf16x8 v = *(const bf16x8*)p;
  float f[8];
  float mx = -1e30f;
#pragma unroll
  for (int j = 0; j < 8; ++j) {
    f[j] = (float)v[j] * 0.03125f;  // 1/sqrt(1024)
    mx = fmaxf(mx, f[j]);
  }
#pragma unroll
  for (int off = 1; off < 64; off <<= 1) mx = fmaxf(mx, __shfl_xor(mx, off));
  float s = 0.f;
#pragma unroll
  for (int j = 0; j < 8; ++j) {
    f[j] = __expf(f[j] - mx);
    s += f[j];
  }
#pragma unroll
  for (int off = 1; off < 64; off <<= 1) s += __shfl_xor(s, off);
  const float inv = 1.0f / s;
  bf16x8 o;
#pragma unroll
  for (int j = 0; j < 8; ++j) o[j] = (__bf16)(f[j] * inv);
  *(bf16x8*)p = o;
}

// ---------------- scores kernel (R5 structure, known-good) ---------------
#define SLOADFRAGS(cb, kk)                                                    \
  {                                                                           \
    const __bf16* As_ = &ldsA[cb][(warp_m * 64 + fr) * 64];                   \
    const __bf16* Bs_ = &ldsB[cb][(warp_n * 64 + fr) * 64];                   \
    const int pg_ = (((kk)*4 + fq) ^ (fr & 7)) * 8;                           \
    _Pragma("unroll") for (int m = 0; m < 4; ++m)                             \
        af[m] = *(const bf16x8*)(As_ + m * 16 * 64 + pg_);                    \
    _Pragma("unroll") for (int n = 0; n < 4; ++n)                             \
        bfv[n] = *(const bf16x8*)(Bs_ + n * 16 * 64 + pg_);                   \
  }

#define SMFMA16(ACC)                                                          \
  {                                                                           \
    __builtin_amdgcn_s_barrier();                                             \
    asm volatile("s_waitcnt lgkmcnt(0)" ::: "memory");                        \
    __builtin_amdgcn_s_setprio(1);                                            \
    _Pragma("unroll") for (int m = 0; m < 4; ++m)                             \
        _Pragma("unroll") for (int n = 0; n < 4; ++n)                         \
            ACC[m][n] = __builtin_amdgcn_mfma_f32_16x16x32_bf16(              \
                af[m], bfv[n], ACC[m][n], 0, 0, 0);                           \
    __builtin_amdgcn_s_setprio(0);                                            \
    __builtin_amdgcn_s_barrier();                                             \
  }

__global__ __launch_bounds__(512, 2) void gemm_scores_kernel(
    const __bf16* __restrict__ xb, const __bf16* __restrict__ mbb,
    __bf16* __restrict__ s1) {
  __shared__ __align__(16) __bf16 ldsA[3][256 * 64];
  __shared__ __align__(16) __bf16 ldsB[3][128 * 64];
  const int tid = threadIdx.x;
  const int lane = tid & 63;
  const int wave = tid >> 6;
  const int bid = blockIdx.x;            // 256 blocks
  const int xcd = bid & 7;
  const int idx = bid >> 3;              // 0..31
  const int bm = xcd * 8 + (idx & 7);    // 0..63
  const int bn = idx >> 3;               // 0..3
  const int row0 = bm * 256;
  const int col0 = bn * 128;
  const int warp_m = wave >> 1;
  const int warp_n = wave & 1;
  const int srow = lane >> 3;
  const int sgc = (lane & 7) ^ srow;
  const int wv32 = wave * 32;
  const int wv16 = wave * 16;
  const int fr = lane & 15;
  const int fq = lane >> 4;

  const __bf16* aS = xb + (size_t)(row0 + wv32 + srow) * EMBED + sgc * 8;
  const __bf16* bS = mbb + (size_t)(col0 + wv16 + srow) * EMBED + sgc * 8;

#define STAGE_S1(vt, buf)                                                     \
  {                                                                           \
    const int k0_ = (vt)*64;                                                  \
    _Pragma("unroll") for (int c = 0; c < 2; ++c)                             \
        GLDS(aS + (size_t)c * 8 * EMBED + k0_, &ldsA[buf][(wv32 + c * 8) * 64]); \
    GLDS(bS + k0_, &ldsB[buf][wv16 * 64]);                                    \
  }
#define STAGE_S2(vt, buf)                                                     \
  {                                                                           \
    const int k0_ = (vt)*64;                                                  \
    _Pragma("unroll") for (int c = 2; c < 4; ++c)                             \
        GLDS(aS + (size_t)c * 8 * EMBED + k0_, &ldsA[buf][(wv32 + c * 8) * 64]); \
    GLDS(bS + (size_t)8 * EMBED + k0_, &ldsB[buf][(wv16 + 8) * 64]);          \
  }

  f32x4 acc[4][4];
#pragma unroll
  for (int m = 0; m < 4; ++m)
#pragma unroll
    for (int n = 0; n < 4; ++n) acc[m][n] = (f32x4){0.f, 0.f, 0.f, 0.f};
  bf16x8 af[4], bfv[4];

  STAGE_S1(0, 0); STAGE_S2(0, 0);
  STAGE_S1(1, 1); STAGE_S2(1, 1);
  asm volatile("s_waitcnt vmcnt(6)" ::: "memory");
  __builtin_amdgcn_s_barrier();

  const int NT = 16;
  for (int vt = 0; vt < NT; ++vt) {
    const int cb = vt % 3;
    const int nb = (vt + 2) % 3;
    SLOADFRAGS(cb, 0);
    if (vt + 2 < NT) STAGE_S1(vt + 2, nb);
    SMFMA16(acc);
    SLOADFRAGS(cb, 1);
    if (vt + 2 < NT) STAGE_S2(vt + 2, nb);
    if (vt < NT - 2) {
      asm volatile("s_waitcnt vmcnt(6)" ::: "memory");
    } else if (vt == NT - 2) {
      asm volatile("s_waitcnt vmcnt(0)" ::: "memory");
    }
    SMFMA16(acc);
  }
#undef STAGE_S1
#undef STAGE_S2

#pragma unroll
  for (int n = 0; n < 4; ++n) {
    const int col = col0 + warp_n * 64 + n * 16 + fr;
#pragma unroll
    for (int m = 0; m < 4; ++m)
#pragma unroll
      for (int j = 0; j < 4; ++j) {
        const int row = row0 + warp_m * 64 + m * 16 + fq * 4 + j;
        s1[(size_t)row * WINDOW + col] = (__bf16)acc[m][n][j];
      }
  }
}

// ============ fused dual GEMM, m201 8-phase schedule =====================
// BM=BN=256, 8 waves (2M x 4N), wave tile 128x64 per acc.
// K-tile BK=64 split in two K-halves (slots [db][kh][256 rows][32 els]).
// Virtual tiles: vt 0..7 retrieved (A=s1,B=mbt,K=512); 8..23 gate
// (A=xb,B=gwb,K=1024). Retrieved acc parked as packed bf16 (64 VGPR).
// Per tile 4 phases (kh,mh), per phase: 4-8 ds_read + 2 glds + [wait] +
// barrier + lgkm(0) + setprio + 16 MFMA + barrier. vmcnt(8) twice/tile.
__global__ __launch_bounds__(512, 2) void dual8_kernel(
    const __bf16* __restrict__ s1, const __bf16* __restrict__ xb,
    const __bf16* __restrict__ mbt, const __bf16* __restrict__ gwb,
    const float* __restrict__ gb, float* __restrict__ out) {
  __shared__ __align__(16) __bf16 ldsA[2][2][256 * 32];  // 64 KB
  __shared__ __align__(16) __bf16 ldsB[2][2][256 * 32];  // 64 KB
  const int tid = threadIdx.x, lane = tid & 63, wave = tid >> 6;
  const int bid = blockIdx.x;                 // 256 blocks
  const int bm = (bid & 7) * 8 + ((bid >> 3) & 7);  // 0..63 (XCD-grouped)
  const int bn = bid >> 6;                    // 0..3
  const int row0 = bm * 256, col0 = bn * 256;
  const int warp_m = wave >> 2;               // 0..1 -> 128 rows
  const int warp_n = wave & 3;                // 0..3 -> 64 cols
  const int fr = lane & 15, fq = lane >> 4;
  // frag-read swizzled granule offset (elems); involution with staging sg
  const int swo = (fq ^ ((fr ^ (fr >> 2)) & 3)) * 8;

  // staging thread map: row = c*128 + tid>>2, source granule pre-swizzled
  const int srow = tid >> 2;  // 0..127
  const int sg = (tid & 3) ^ ((tid >> 2) & 3) ^ ((tid >> 4) & 3);
  const __bf16* aRb = s1 + (size_t)(row0 + srow) * WINDOW + sg * 8;
  const __bf16* aGb = xb + (size_t)(row0 + srow) * EMBED + sg * 8;
  const __bf16* bRb = mbt + (size_t)(col0 + srow) * WINDOW + sg * 8;
  const __bf16* bGb = gwb + (size_t)(col0 + srow) * EMBED + sg * 8;

#define STG_A(vt, kh)                                                         \
  {                                                                           \
    const int db_ = (vt)&1;                                                   \
    if ((vt) < 8) {                                                           \
      const int ko = (vt)*64 + (kh)*32;                                       \
      GLDS(aRb + ko, &ldsA[db_][kh][tid * 8]);                                \
      GLDS(aRb + (size_t)128 * WINDOW + ko, &ldsA[db_][kh][4096 + tid * 8]);  \
    } else {                                                                  \
      const int ko = ((vt)-8) * 64 + (kh)*32;                                 \
      GLDS(aGb + ko, &ldsA[db_][kh][tid * 8]);                                \
      GLDS(aGb + (size_t)128 * EMBED + ko, &ldsA[db_][kh][4096 + tid * 8]);   \
    }                                                                         \
  }
#define STG_B(vt, kh)                                                         \
  {                                                                           \
    const int db_ = (vt)&1;                                                   \
    if ((vt) < 8) {                                                           \
      const int ko = (vt)*64 + (kh)*32;                                       \
      GLDS(bRb + ko, &ldsB[db_][kh][tid * 8]);                                \
      GLDS(bRb + (size_t)128 * WINDOW + ko, &ldsB[db_][kh][4096 + tid * 8]);  \
    } else {                                                                  \
      const int ko = ((vt)-8) * 64 + (kh)*32;                                 \
      GLDS(bGb + ko, &ldsB[db_][kh][tid * 8]);                                \
      GLDS(bGb + (size_t)128 * EMBED + ko, &ldsB[db_][kh][4096 + tid * 8]);   \
    }                                                                         \
  }

#define WAIT8 asm volatile("s_waitcnt vmcnt(8)" ::: "memory")
#define WAIT4 asm volatile("s_waitcnt vmcnt(4)" ::: "memory")
#define WAIT0 asm volatile("s_waitcnt vmcnt(0)" ::: "memory")

#define PH(ACC, db, kh, mh, LOADB, STG, WAITX)                                \
  {                                                                           \
    _Pragma("unroll") for (int m = 0; m < 4; ++m) {                           \
      const int lr = warp_m * 128 + (mh)*64 + m * 16 + fr;                    \
      af[m] = *(const bf16x8*)&ldsA[db][kh][lr * 32 + swo];                   \
    }                                                                         \
    if (LOADB) {                                                              \
      _Pragma("unroll") for (int n = 0; n < 4; ++n) {                         \
        const int lrB = warp_n * 64 + n * 16 + fr;                            \
        bfv[n] = *(const bf16x8*)&ldsB[db][kh][lrB * 32 + swo];               \
      }                                                                       \
    }                                                                         \
    STG;                                                                      \
    WAITX;                                                                    \
    __builtin_amdgcn_s_barrier();                                             \
    asm volatile("s_waitcnt lgkmcnt(0)" ::: "memory");                        \
    __builtin_amdgcn_s_setprio(1);                                            \
    _Pragma("unroll") for (int m = 0; m < 4; ++m)                             \
        _Pragma("unroll") for (int n = 0; n < 4; ++n)                         \
            ACC[(mh)*4 + m][n] = __builtin_amdgcn_mfma_f32_16x16x32_bf16(     \
                af[m], bfv[n], ACC[(mh)*4 + m][n], 0, 0, 0);                  \
    __builtin_amdgcn_s_setprio(0);                                            \
    __builtin_amdgcn_s_barrier();                                             \
  }

#define TILE(ACC, vt, W1, W3)                                                 \
  {                                                                           \
    const int db = (vt)&1;                                                    \
    PH(ACC, db, 0, 0, 1, { if ((vt) + 1 < 24) STG_A((vt) + 1, 1); }, {});     \
    PH(ACC, db, 0, 1, 0, { if ((vt) + 1 < 24) STG_B((vt) + 1, 1); }, W1);     \
    PH(ACC, db, 1, 0, 1, { if ((vt) + 2 < 24) STG_A((vt) + 2, 0); }, {});     \
    PH(ACC, db, 1, 1, 0, { if ((vt) + 2 < 24) STG_B((vt) + 2, 0); }, W3);     \
  }

  bf16x8 af[4], bfv[4];
  f32x4 accr[8][4];
#pragma unroll
  for (int m = 0; m < 8; ++m)
#pragma unroll
    for (int n = 0; n < 4; ++n) accr[m][n] = (f32x4){0.f, 0.f, 0.f, 0.f};

  // prologue: (0,kh0) (0,kh1) (1,kh0); wait oldest 4 done
  STG_A(0, 0); STG_B(0, 0);
  STG_A(0, 1); STG_B(0, 1);
  STG_A(1, 0); STG_B(1, 0);
  WAIT8;
  __builtin_amdgcn_s_barrier();

  // retrieved: vt 0..7
  for (int vt = 0; vt < 8; ++vt) TILE(accr, vt, WAIT8, WAIT8);

  // park retrieved as packed bf16 (2 f32 -> 1 u32)
  unsigned pk[8][4][2];
#pragma unroll
  for (int m = 0; m < 8; ++m)
#pragma unroll
    for (int n = 0; n < 4; ++n) {
      unsigned b0 = (unsigned)__builtin_bit_cast(unsigned short, (__bf16)accr[m][n][0]);
      unsigned b1 = (unsigned)__builtin_bit_cast(unsigned short, (__bf16)accr[m][n][1]);
      unsigned b2 = (unsigned)__builtin_bit_cast(unsigned short, (__bf16)accr[m][n][2]);
      unsigned b3 = (unsigned)__builtin_bit_cast(unsigned short, (__bf16)accr[m][n][3]);
      pk[m][n][0] = (b1 << 16) | b0;
      pk[m][n][1] = (b3 << 16) | b2;
    }

  f32x4 accg[8][4];
#pragma unroll
  for (int m = 0; m < 8; ++m)
#pragma unroll
    for (int n = 0; n < 4; ++n) accg[m][n] = (f32x4){0.f, 0.f, 0.f, 0.f};

  // gate: vt 8..23 (tail waits: vt==22 -> W3=vmcnt(4); vt==23 -> W1=0, W3 none)
  for (int vt = 8; vt < 22; ++vt) TILE(accg, vt, WAIT8, WAIT8);
  TILE(accg, 22, WAIT8, WAIT4);
  TILE(accg, 23, WAIT0, {});

#undef TILE
#undef PH
#undef STG_A
#undef STG_B

  // epilogue: g = sigmoid(accg + gb); out = g*x + (1-g)*retrieved
#pragma unroll
  for (int n = 0; n < 4; ++n) {
    const int col = col0 + warp_n * 64 + n * 16 + fr;
    const float bias = gb[col];
#pragma unroll
    for (int m = 0; m < 8; ++m) {
      float rv[4];
      rv[0] = __builtin_bit_cast(float, pk[m][n][0] << 16);
      rv[1] = __builtin_bit_cast(float, pk[m][n][0] & 0xffff0000u);
      rv[2] = __builtin_bit_cast(float, pk[m][n][1] << 16);
      rv[3] = __builtin_bit_cast(float, pk[m][n][1] & 0xffff0000u);
#pragma unroll
      for (int j = 0; j < 4; ++j) {
        const int row = row0 + warp_m * 128 + m * 16 + fq * 4 + j;
        const size_t o = (size_t)row * EMBED + col;
        const float g = 1.0f / (1.0f + __expf(-(accg[m][n][j] + bias)));
        const float xv = (float)xb[o];
        out[o] = g * xv + (1.0f - g) * rv[j];
      }
    }
  }
}

extern "C" void kernel_launch(void* const* d_in, const int* in_sizes, int n_in,
                              void* d_out, int out_size, void* d_ws,
                              size_t ws_size, hipStream_t stream) {
  const float* x = (const float*)d_in[0];
  const float* mb = (const float*)d_in[1];
  const float* gw = (const float*)d_in[2];
  const float* gb = (const float*)d_in[3];
  float* out = (float*)d_out;

  char* ws = (char*)d_ws;
  __bf16* xb = (__bf16*)(ws);                   // 16384*1024*2 = 33,554,432
  __bf16* mbb = (__bf16*)(ws + 33554432);       // 512*1024*2  =  1,048,576
  __bf16* mbt = (__bf16*)(ws + 34603008);       // 1024*512*2  =  1,048,576
  __bf16* gwb = (__bf16*)(ws + 35651584);       // 1024*1024*2 =  2,097,152
  __bf16* s1 = (__bf16*)(ws + 37748736);        // 16384*512*2 = 16,777,216
  // total 54,525,952 bytes

  cast_bf16_kernel<<<8192, 256, 0, stream>>>(x, xb, 2097152);
  cast_bf16_kernel<<<256, 256, 0, stream>>>(mb, mbb, 65536);
  cast_bf16_kernel<<<512, 256, 0, stream>>>(gw, gwb, 131072);
  transpose_mb_kernel<<<2048, 256, 0, stream>>>(mb, mbt);
  gemm_scores_kernel<<<256, 512, 0, stream>>>(xb, mbb, s1);
  softmax_kernel<<<4096, 256, 0, stream>>>(s1);
  dual8_kernel<<<256, 512, 0, stream>>>(s1, xb, mbt, gwb, gb, out);
}

// Round 8
// 124.431 us; speedup vs baseline: 1.3900x; 1.3900x over previous
//
#include <hip/hip_runtime.h>
#include <hip/hip_bf16.h>

#define EMBED 1024
#define WINDOW 512
#define NROWS 16384  // 4 * 4096

typedef __attribute__((ext_vector_type(4))) float f32x4;
typedef __bf16 bf16x8 __attribute__((ext_vector_type(8)));

#define GLDS(g, l)                                                        \
  __builtin_amdgcn_global_load_lds(                                       \
      (const __attribute__((address_space(1))) void*)(const void*)(g),    \
      (__attribute__((address_space(3))) void*)(void*)(l), 16, 0, 0)

// ---------------- prep: fp32 -> bf16 cast, 8 elems/thread ----------------
__global__ __launch_bounds__(256) void cast_bf16_kernel(
    const float* __restrict__ in, __bf16* __restrict__ out, int n8) {
  int i = blockIdx.x * blockDim.x + threadIdx.x;
  if (i >= n8) return;
  const f32x4* p = (const f32x4*)(in + (size_t)i * 8);
  f32x4 a = p[0], b = p[1];
  bf16x8 o = {(__bf16)a[0], (__bf16)a[1], (__bf16)a[2], (__bf16)a[3],
              (__bf16)b[0], (__bf16)b[1], (__bf16)b[2], (__bf16)b[3]};
  *(bf16x8*)(out + (size_t)i * 8) = o;
}

// ---------------- prep: MB [512][1024] fp32 -> MB^T [1024][512] bf16 ------
__global__ __launch_bounds__(256) void transpose_mb_kernel(
    const float* __restrict__ mb, __bf16* __restrict__ mbt) {
  int idx = blockIdx.x * blockDim.x + threadIdx.x;  // over 512*1024
  int w = idx >> 10, d = idx & 1023;
  mbt[(size_t)d * WINDOW + w] = (__bf16)mb[idx];
}

// ---------------- softmax in-place on S1 rows (512 wide) -----------------
__global__ __launch_bounds__(256) void softmax_kernel(__bf16* __restrict__ s1) {
  const int row = blockIdx.x * 4 + (threadIdx.x >> 6);
  const int lane = threadIdx.x & 63;
  __bf16* p = s1 + (size_t)row * WINDOW + lane * 8;
  bf16x8 v = *(const bf16x8*)p;
  float f[8];
  float mx = -1e30f;
#pragma unroll
  for (int j = 0; j < 8; ++j) {
    f[j] = (float)v[j] * 0.03125f;  // 1/sqrt(1024)
    mx = fmaxf(mx, f[j]);
  }
#pragma unroll
  for (int off = 1; off < 64; off <<= 1) mx = fmaxf(mx, __shfl_xor(mx, off));
  float s = 0.f;
#pragma unroll
  for (int j = 0; j < 8; ++j) {
    f[j] = __expf(f[j] - mx);
    s += f[j];
  }
#pragma unroll
  for (int off = 1; off < 64; off <<= 1) s += __shfl_xor(s, off);
  const float inv = 1.0f / s;
  bf16x8 o;
#pragma unroll
  for (int j = 0; j < 8; ++j) o[j] = (__bf16)(f[j] * inv);
  *(bf16x8*)p = o;
}

// ---------------- scores kernel (R5 structure, known-good) ---------------
#define SLOADFRAGS(cb, kk)                                                    \
  {                                                                           \
    const __bf16* As_ = &ldsA[cb][(warp_m * 64 + fr) * 64];                   \
    const __bf16* Bs_ = &ldsB[cb][(warp_n * 64 + fr) * 64];                   \
    const int pg_ = (((kk)*4 + fq) ^ (fr & 7)) * 8;                           \
    _Pragma("unroll") for (int m = 0; m < 4; ++m)                             \
        af[m] = *(const bf16x8*)(As_ + m * 16 * 64 + pg_);                    \
    _Pragma("unroll") for (int n = 0; n < 4; ++n)                             \
        bfv[n] = *(const bf16x8*)(Bs_ + n * 16 * 64 + pg_);                   \
  }

#define SMFMA16(ACC)                                                          \
  {                                                                           \
    __builtin_amdgcn_s_barrier();                                             \
    asm volatile("s_waitcnt lgkmcnt(0)" ::: "memory");                        \
    __builtin_amdgcn_s_setprio(1);                                            \
    _Pragma("unroll") for (int m = 0; m < 4; ++m)                             \
        _Pragma("unroll") for (int n = 0; n < 4; ++n)                         \
            ACC[m][n] = __builtin_amdgcn_mfma_f32_16x16x32_bf16(              \
                af[m], bfv[n], ACC[m][n], 0, 0, 0);                           \
    __builtin_amdgcn_s_setprio(0);                                            \
    __builtin_amdgcn_s_barrier();                                             \
  }

__global__ __launch_bounds__(512, 2) void gemm_scores_kernel(
    const __bf16* __restrict__ xb, const __bf16* __restrict__ mbb,
    __bf16* __restrict__ s1) {
  __shared__ __align__(16) __bf16 ldsA[3][256 * 64];
  __shared__ __align__(16) __bf16 ldsB[3][128 * 64];
  const int tid = threadIdx.x;
  const int lane = tid & 63;
  const int wave = tid >> 6;
  const int bid = blockIdx.x;            // 256 blocks
  const int xcd = bid & 7;
  const int idx = bid >> 3;              // 0..31
  const int bm = xcd * 8 + (idx & 7);    // 0..63
  const int bn = idx >> 3;               // 0..3
  const int row0 = bm * 256;
  const int col0 = bn * 128;
  const int warp_m = wave >> 1;
  const int warp_n = wave & 1;
  const int srow = lane >> 3;
  const int sgc = (lane & 7) ^ srow;
  const int wv32 = wave * 32;
  const int wv16 = wave * 16;
  const int fr = lane & 15;
  const int fq = lane >> 4;

  const __bf16* aS = xb + (size_t)(row0 + wv32 + srow) * EMBED + sgc * 8;
  const __bf16* bS = mbb + (size_t)(col0 + wv16 + srow) * EMBED + sgc * 8;

#define STAGE_S1(vt, buf)                                                     \
  {                                                                           \
    const int k0_ = (vt)*64;                                                  \
    _Pragma("unroll") for (int c = 0; c < 2; ++c)                             \
        GLDS(aS + (size_t)c * 8 * EMBED + k0_, &ldsA[buf][(wv32 + c * 8) * 64]); \
    GLDS(bS + k0_, &ldsB[buf][wv16 * 64]);                                    \
  }
#define STAGE_S2(vt, buf)                                                     \
  {                                                                           \
    const int k0_ = (vt)*64;                                                  \
    _Pragma("unroll") for (int c = 2; c < 4; ++c)                             \
        GLDS(aS + (size_t)c * 8 * EMBED + k0_, &ldsA[buf][(wv32 + c * 8) * 64]); \
    GLDS(bS + (size_t)8 * EMBED + k0_, &ldsB[buf][(wv16 + 8) * 64]);          \
  }

  f32x4 acc[4][4];
#pragma unroll
  for (int m = 0; m < 4; ++m)
#pragma unroll
    for (int n = 0; n < 4; ++n) acc[m][n] = (f32x4){0.f, 0.f, 0.f, 0.f};
  bf16x8 af[4], bfv[4];

  STAGE_S1(0, 0); STAGE_S2(0, 0);
  STAGE_S1(1, 1); STAGE_S2(1, 1);
  asm volatile("s_waitcnt vmcnt(6)" ::: "memory");
  __builtin_amdgcn_s_barrier();

  const int NT = 16;
  for (int vt = 0; vt < NT; ++vt) {
    const int cb = vt % 3;
    const int nb = (vt + 2) % 3;
    SLOADFRAGS(cb, 0);
    if (vt + 2 < NT) STAGE_S1(vt + 2, nb);
    SMFMA16(acc);
    SLOADFRAGS(cb, 1);
    if (vt + 2 < NT) STAGE_S2(vt + 2, nb);
    if (vt < NT - 2) {
      asm volatile("s_waitcnt vmcnt(6)" ::: "memory");
    } else if (vt == NT - 2) {
      asm volatile("s_waitcnt vmcnt(0)" ::: "memory");
    }
    SMFMA16(acc);
  }
#undef STAGE_S1
#undef STAGE_S2

#pragma unroll
  for (int n = 0; n < 4; ++n) {
    const int col = col0 + warp_n * 64 + n * 16 + fr;
#pragma unroll
    for (int m = 0; m < 4; ++m)
#pragma unroll
      for (int j = 0; j < 4; ++j) {
        const int row = row0 + warp_m * 64 + m * 16 + fq * 4 + j;
        s1[(size_t)row * WINDOW + col] = (__bf16)acc[m][n][j];
      }
  }
}

// ======= fused dual GEMM + blend: 4 waves, 128x128, dbuf, 2 blocks/CU ====
// Virtual tiles: vt 0..7 retrieved (A=s1,B=mbt,K=512); vt 8..23 gate
// (A=xb,B=gwb,K=1024). BK=64, double-buffered 64KB LDS, counted vmcnt(8)
// (one tile = 8 glds/wave in flight; never drain mid-loop). 2 barriers/tile.
// Swizzle: R5's verified 8-granule involution (0 conflicts): staging source
// granule (lane&7)^(lane>>3); frag read granule (kk*4+fq)^(fr&7).
__global__ __launch_bounds__(256, 2) void dual_fused128_kernel(
    const __bf16* __restrict__ s1, const __bf16* __restrict__ xb,
    const __bf16* __restrict__ mbt, const __bf16* __restrict__ gwb,
    const float* __restrict__ gb, float* __restrict__ out) {
  __shared__ __align__(16) __bf16 ldsA[2][128 * 64];  // 32 KB
  __shared__ __align__(16) __bf16 ldsB[2][128 * 64];  // 32 KB
  const int tid = threadIdx.x, lane = tid & 63, wave = tid >> 6;
  // XCD-grouped bijection over 1024 blocks: xcd gets bm in [xcd*16, +16)
  const int bid = blockIdx.x;
  const int xcd = bid & 7;
  const int g = bid >> 3;                  // 0..127
  const int bm = xcd * 16 + (g & 15);      // 0..127
  const int bn = g >> 4;                   // 0..7
  const int row0 = bm * 128, col0 = bn * 128;
  const int warp_m = wave >> 1, warp_n = wave & 1;  // 2x2 waves, 64x64 tiles
  const int fr = lane & 15, fq = lane >> 4;
  const int srow = lane >> 3;              // 0..7
  const int sgc = (lane & 7) ^ srow;       // pre-swizzled source granule
  const int wv32 = wave * 32;

  const __bf16* aR = s1 + (size_t)(row0 + wv32 + srow) * WINDOW + sgc * 8;
  const __bf16* bR = mbt + (size_t)(col0 + wv32 + srow) * WINDOW + sgc * 8;
  const __bf16* aG = xb + (size_t)(row0 + wv32 + srow) * EMBED + sgc * 8;
  const __bf16* bG = gwb + (size_t)(col0 + wv32 + srow) * EMBED + sgc * 8;

  // per wave per tile: 4 A-glds + 4 B-glds (8 rows each), rows wv32..wv32+31
#define STG(vt, buf)                                                          \
  {                                                                           \
    if ((vt) < 8) {                                                           \
      const int k0_ = (vt)*64;                                                \
      _Pragma("unroll") for (int c = 0; c < 4; ++c)                           \
          GLDS(aR + (size_t)c * 8 * WINDOW + k0_,                             \
               &ldsA[buf][(wv32 + c * 8) * 64]);                              \
      _Pragma("unroll") for (int c = 0; c < 4; ++c)                           \
          GLDS(bR + (size_t)c * 8 * WINDOW + k0_,                             \
               &ldsB[buf][(wv32 + c * 8) * 64]);                              \
    } else {                                                                  \
      const int k0_ = ((vt)-8) * 64;                                          \
      _Pragma("unroll") for (int c = 0; c < 4; ++c)                           \
          GLDS(aG + (size_t)c * 8 * EMBED + k0_,                              \
               &ldsA[buf][(wv32 + c * 8) * 64]);                              \
      _Pragma("unroll") for (int c = 0; c < 4; ++c)                           \
          GLDS(bG + (size_t)c * 8 * EMBED + k0_,                              \
               &ldsB[buf][(wv32 + c * 8) * 64]);                              \
    }                                                                         \
  }

#define BARF                                                                  \
  {                                                                           \
    asm volatile("" ::: "memory");                                            \
    __builtin_amdgcn_s_barrier();                                             \
    asm volatile("" ::: "memory");                                            \
  }

#define COMPUTE(ACC, cur)                                                     \
  {                                                                           \
    const __bf16* As_ = &ldsA[cur][(warp_m * 64 + fr) * 64];                  \
    const __bf16* Bs_ = &ldsB[cur][(warp_n * 64 + fr) * 64];                  \
    _Pragma("unroll") for (int kk = 0; kk < 2; ++kk) {                        \
      const int pg_ = ((kk * 4 + fq) ^ (fr & 7)) * 8;                         \
      bf16x8 af[4], bfv[4];                                                   \
      _Pragma("unroll") for (int m = 0; m < 4; ++m)                           \
          af[m] = *(const bf16x8*)(As_ + m * 16 * 64 + pg_);                  \
      _Pragma("unroll") for (int n = 0; n < 4; ++n)                           \
          bfv[n] = *(const bf16x8*)(Bs_ + n * 16 * 64 + pg_);                 \
      __builtin_amdgcn_s_setprio(1);                                          \
      _Pragma("unroll") for (int m = 0; m < 4; ++m)                           \
          _Pragma("unroll") for (int n = 0; n < 4; ++n)                       \
              ACC[m][n] = __builtin_amdgcn_mfma_f32_16x16x32_bf16(            \
                  af[m], bfv[n], ACC[m][n], 0, 0, 0);                         \
      __builtin_amdgcn_s_setprio(0);                                          \
    }                                                                         \
  }

  f32x4 accr[4][4], accg[4][4];
#pragma unroll
  for (int m = 0; m < 4; ++m)
#pragma unroll
    for (int n = 0; n < 4; ++n) {
      accr[m][n] = (f32x4){0.f, 0.f, 0.f, 0.f};
      accg[m][n] = (f32x4){0.f, 0.f, 0.f, 0.f};
    }

  STG(0, 0);
  // retrieved: vt 0..7 (accr)
  for (int vt = 0; vt < 8; ++vt) {
    const int cur = vt & 1;
    STG(vt + 1, cur ^ 1);
    asm volatile("s_waitcnt vmcnt(8)" ::: "memory");  // tile-vt loads done
    BARF;
    COMPUTE(accr, cur);
    BARF;  // all waves done reading buf cur before next STG overwrites it
  }
  // gate: vt 8..23 (accg)
  for (int vt = 8; vt < 24; ++vt) {
    const int cur = vt & 1;
    if (vt + 1 < 24) {
      STG(vt + 1, cur ^ 1);
      asm volatile("s_waitcnt vmcnt(8)" ::: "memory");
    } else {
      asm volatile("s_waitcnt vmcnt(0)" ::: "memory");
    }
    BARF;
    COMPUTE(accg, cur);
    BARF;
  }
#undef STG
#undef COMPUTE
#undef BARF

  // epilogue: g = sigmoid(accg + gb); out = g*x + (1-g)*accr
#pragma unroll
  for (int n = 0; n < 4; ++n) {
    const int col = col0 + warp_n * 64 + n * 16 + fr;
    const float bias = gb[col];
#pragma unroll
    for (int m = 0; m < 4; ++m) {
#pragma unroll
      for (int j = 0; j < 4; ++j) {
        const int row = row0 + warp_m * 64 + m * 16 + fq * 4 + j;
        const size_t o = (size_t)row * EMBED + col;
        const float gt = 1.0f / (1.0f + __expf(-(accg[m][n][j] + bias)));
        const float xv = (float)xb[o];
        out[o] = gt * xv + (1.0f - gt) * accr[m][n][j];
      }
    }
  }
}

extern "C" void kernel_launch(void* const* d_in, const int* in_sizes, int n_in,
                              void* d_out, int out_size, void* d_ws,
                              size_t ws_size, hipStream_t stream) {
  const float* x = (const float*)d_in[0];
  const float* mb = (const float*)d_in[1];
  const float* gw = (const float*)d_in[2];
  const float* gb = (const float*)d_in[3];
  float* out = (float*)d_out;

  char* ws = (char*)d_ws;
  __bf16* xb = (__bf16*)(ws);                   // 16384*1024*2 = 33,554,432
  __bf16* mbb = (__bf16*)(ws + 33554432);       // 512*1024*2  =  1,048,576
  __bf16* mbt = (__bf16*)(ws + 34603008);       // 1024*512*2  =  1,048,576
  __bf16* gwb = (__bf16*)(ws + 35651584);       // 1024*1024*2 =  2,097,152
  __bf16* s1 = (__bf16*)(ws + 37748736);        // 16384*512*2 = 16,777,216
  // total 54,525,952 bytes

  cast_bf16_kernel<<<8192, 256, 0, stream>>>(x, xb, 2097152);
  cast_bf16_kernel<<<256, 256, 0, stream>>>(mb, mbb, 65536);
  cast_bf16_kernel<<<512, 256, 0, stream>>>(gw, gwb, 131072);
  transpose_mb_kernel<<<2048, 256, 0, stream>>>(mb, mbt);
  gemm_scores_kernel<<<256, 512, 0, stream>>>(xb, mbb, s1);
  softmax_kernel<<<4096, 256, 0, stream>>>(s1);
  dual_fused128_kernel<<<1024, 256, 0, stream>>>(s1, xb, mbt, gwb, gb, out);
}